// Round 2
// baseline (22.054 us; speedup 1.0000x reference)
//
#include <hip/hip_runtime.h>
#include <math.h>

#define NN 4096
#define ALPHA_C 1.0f
#define H_COUP_C 0.1f
#define DT_C 0.01f

// prep: per column j build uv = (u,v) and the amplitude-phase form
// (r, phi) with r = sqrt(u^2+v^2), phi = atan2(v,u), so that
// sin(p)*u + cos(p)*v == r * sin(p + phi).
__global__ void prep_uv(const float* __restrict__ x_old,
                        const float* __restrict__ y_old,
                        const float* __restrict__ b,
                        float2* __restrict__ rphi,
                        float2* __restrict__ uv) {
    int j = blockIdx.x * blockDim.x + threadIdx.x;
    if (j >= NN) return;
    const int half = NN / 2;
    float u, v;
    if (j < half) {
        u = x_old[2 * j];
        v = x_old[2 * j + 1];
    } else {
        int k = 2 * (j - half);
        u = y_old[k]     - b[k];
        v = y_old[k + 1] - b[k + 1];
    }
    uv[j] = make_float2(u, v);
    float r = sqrtf(u * u + v * v);
    float phi = atan2f(v, u);
    rphi[j] = make_float2(r, phi);
}

__global__ __launch_bounds__(256) void cpg_row(
        const float* __restrict__ pd,
        const float2* __restrict__ rphi,
        const float2* __restrict__ uv,
        const float* __restrict__ x_old,
        const float* __restrict__ y_old,
        const float* __restrict__ x_old_dot,
        const float* __restrict__ omega,
        const float* __restrict__ A,
        const float* __restrict__ b,
        const float* __restrict__ h_a,
        const float* __restrict__ y_state,
        float* __restrict__ out) {
    const int i = blockIdx.x;
    const int tid = threadIdx.x;
    const float* row = pd + (size_t)i * NN;
    const float* rpf = reinterpret_cast<const float*>(rphi);

    float acc = 0.0f;
    // 4096 elements / (256 threads * 4 per thread) = 4 float4 iterations
    #pragma unroll
    for (int k = 0; k < 4; ++k) {
        const int jb = (k * 256 + tid) * 4;
        float4 p4 = *reinterpret_cast<const float4*>(row + jb);
        float4 a4 = *reinterpret_cast<const float4*>(rpf + 2 * jb);      // r0 p0 r1 p1
        float4 b4 = *reinterpret_cast<const float4*>(rpf + 2 * jb + 4);  // r2 p2 r3 p3
        acc = fmaf(a4.x, __sinf(p4.x + a4.y), acc);
        acc = fmaf(a4.z, __sinf(p4.y + a4.w), acc);
        acc = fmaf(b4.x, __sinf(p4.z + b4.y), acc);
        acc = fmaf(b4.z, __sinf(p4.w + b4.w), acc);
    }

    // wave (64-lane) butterfly reduce
    #pragma unroll
    for (int off = 32; off > 0; off >>= 1)
        acc += __shfl_xor(acc, off, 64);

    __shared__ float wsum[4];
    const int wid = tid >> 6;
    if ((tid & 63) == 0) wsum[wid] = acc;
    __syncthreads();

    if (tid == 0) {
        float total = wsum[0] + wsum[1] + wsum[2] + wsum[3];
        // correct the diagonal: reference forces pd_ii = 0 -> contribution v_i,
        // loop added r_i*sin(pd_ii + phi_i) instead.
        float2 uvi = uv[i];
        float2 rpi = rphi[i];
        float diag = rpi.x * __sinf(row[i] + rpi.y);
        total = total - diag + uvi.y;

        float xo = x_old[i], yo = y_old[i], bi = b[i];
        float ym = yo - bi;
        float r_sq = xo * xo + ym * ym;
        float kd = ALPHA_C * (1.0f - r_sq);
        float zeta = 1.0f - h_a[i] * (xo / (fabsf(x_old_dot[i]) + 1e-9f));
        float wz = omega[i] / zeta;
        float dot = kd * uvi.y + wz * uvi.x + H_COUP_C * total;
        float m = 2.0f * omega[i];
        dot = fminf(fmaxf(dot, -m), m);
        float y_new = y_state[i] + (dot + bi) * DT_C;
        out[i] = A[i] * y_new;
    }
}

extern "C" void kernel_launch(void* const* d_in, const int* in_sizes, int n_in,
                              void* d_out, int out_size, void* d_ws, size_t ws_size,
                              hipStream_t stream) {
    const float* x_old     = (const float*)d_in[0];
    const float* y_old     = (const float*)d_in[1];
    const float* x_old_dot = (const float*)d_in[2];
    const float* omega     = (const float*)d_in[3];
    const float* A         = (const float*)d_in[4];
    const float* b         = (const float*)d_in[5];
    const float* h_a       = (const float*)d_in[6];
    const float* pd        = (const float*)d_in[7];
    const float* y_state   = (const float*)d_in[9];
    float* out = (float*)d_out;
    float2* rphi = (float2*)d_ws;
    float2* uv   = (float2*)((char*)d_ws + NN * sizeof(float2));

    prep_uv<<<NN / 256, 256, 0, stream>>>(x_old, y_old, b, rphi, uv);
    cpg_row<<<NN, 256, 0, stream>>>(pd, rphi, uv, x_old, y_old, x_old_dot,
                                    omega, A, b, h_a, y_state, out);
}

// Round 3
// 21.776 us; speedup vs baseline: 1.0128x; 1.0128x over previous
//
#include <hip/hip_runtime.h>
#include <math.h>

#define NN 4096
#define ALPHA_C 1.0f
#define H_COUP_C 0.1f
#define DT_C 0.01f
#define RPB 4   // rows per block

// prep: per column j build uv=(u,v) and amplitude-phase (r,phi):
// sin(p)*u + cos(p)*v == r*sin(p+phi)
__global__ void prep_uv(const float* __restrict__ x_old,
                        const float* __restrict__ y_old,
                        const float* __restrict__ b,
                        float2* __restrict__ rphi,
                        float2* __restrict__ uv) {
    int j = blockIdx.x * blockDim.x + threadIdx.x;
    if (j >= NN) return;
    const int half = NN / 2;
    float u, v;
    if (j < half) {
        u = x_old[2 * j];
        v = x_old[2 * j + 1];
    } else {
        int k = 2 * (j - half);
        u = y_old[k]     - b[k];
        v = y_old[k + 1] - b[k + 1];
    }
    uv[j] = make_float2(u, v);
    float r = sqrtf(u * u + v * v);
    float phi = atan2f(v, u);
    rphi[j] = make_float2(r, phi);
}

__global__ __launch_bounds__(256) void cpg_rows(
        const float* __restrict__ pd,
        const float2* __restrict__ rphi,
        const float2* __restrict__ uv,
        const float* __restrict__ x_old,
        const float* __restrict__ y_old,
        const float* __restrict__ x_old_dot,
        const float* __restrict__ omega,
        const float* __restrict__ A,
        const float* __restrict__ b,
        const float* __restrict__ h_a,
        const float* __restrict__ y_state,
        float* __restrict__ out) {
    const int tid = threadIdx.x;

    // LDS: rphi table, transposed layout: slot s(j) = (j>>2) + (j&3)*1024
    // so per-element reads (j = 4*lane_group + e) are 8B-stride -> conflict-free.
    __shared__ float lds_rp[2 * NN];        // 32 KB
    __shared__ float wsum[4][RPB];          // [wave][row]

    // Phase A: stage rphi -> LDS (8 float4 per thread)
    const float4* g4 = reinterpret_cast<const float4*>(rphi);  // 2048 float4
    #pragma unroll
    for (int k = 0; k < 8; ++k) {
        int m = k * 256 + tid;
        float4 t4 = g4[m];                  // rphi[2m], rphi[2m+1]
        int s0 = (m >> 1) + (m & 1) * 2048; // slot of j=2m
        int s1 = s0 + 1024;                 // slot of j=2m+1
        *reinterpret_cast<float2*>(&lds_rp[2 * s0]) = make_float2(t4.x, t4.y);
        *reinterpret_cast<float2*>(&lds_rp[2 * s1]) = make_float2(t4.z, t4.w);
    }
    __syncthreads();

    // Phase B: 4 rows per block, k-outer so each LDS read feeds 4 rows
    const int row0 = blockIdx.x * RPB;
    const float* __restrict__ prow = pd + (size_t)row0 * NN;
    float acc[RPB] = {0.f, 0.f, 0.f, 0.f};
    #pragma unroll
    for (int k = 0; k < 4; ++k) {
        const int sbase = k * 256 + tid;    // = jb>>2
        const int jb = sbase * 4;
        float2 rp0 = *reinterpret_cast<const float2*>(&lds_rp[2 * sbase]);
        float2 rp1 = *reinterpret_cast<const float2*>(&lds_rp[2 * (sbase + 1024)]);
        float2 rp2 = *reinterpret_cast<const float2*>(&lds_rp[2 * (sbase + 2048)]);
        float2 rp3 = *reinterpret_cast<const float2*>(&lds_rp[2 * (sbase + 3072)]);
        #pragma unroll
        for (int r = 0; r < RPB; ++r) {
            float4 p4 = *reinterpret_cast<const float4*>(prow + (size_t)r * NN + jb);
            float a = acc[r];
            a = fmaf(rp0.x, __sinf(p4.x + rp0.y), a);
            a = fmaf(rp1.x, __sinf(p4.y + rp1.y), a);
            a = fmaf(rp2.x, __sinf(p4.z + rp2.y), a);
            a = fmaf(rp3.x, __sinf(p4.w + rp3.y), a);
            acc[r] = a;
        }
    }

    // wave butterfly reduce, per row
    #pragma unroll
    for (int r = 0; r < RPB; ++r) {
        #pragma unroll
        for (int off = 32; off > 0; off >>= 1)
            acc[r] += __shfl_xor(acc[r], off, 64);
    }
    const int wid = tid >> 6;
    if ((tid & 63) == 0) {
        #pragma unroll
        for (int r = 0; r < RPB; ++r) wsum[wid][r] = acc[r];
    }
    __syncthreads();

    if (tid < RPB) {
        const int r = tid;
        const int i = row0 + r;
        float total = wsum[0][r] + wsum[1][r] + wsum[2][r] + wsum[3][r];
        // diagonal: reference forces pd_ii=0 -> contribution v_i; loop added
        // r_i*sin(pd_ii+phi_i) instead.
        float2 uvi = uv[i];
        float2 rpi = rphi[i];
        float diag = rpi.x * __sinf(pd[(size_t)i * NN + i] + rpi.y);
        total = total - diag + uvi.y;

        float xo = x_old[i], yo = y_old[i], bi = b[i];
        float ym = yo - bi;
        float r_sq = xo * xo + ym * ym;
        float kd = ALPHA_C * (1.0f - r_sq);
        float zeta = 1.0f - h_a[i] * (xo / (fabsf(x_old_dot[i]) + 1e-9f));
        float wz = omega[i] / zeta;
        float dot = kd * uvi.y + wz * uvi.x + H_COUP_C * total;
        float m = 2.0f * omega[i];
        dot = fminf(fmaxf(dot, -m), m);
        float y_new = y_state[i] + (dot + bi) * DT_C;
        out[i] = A[i] * y_new;
    }
}

extern "C" void kernel_launch(void* const* d_in, const int* in_sizes, int n_in,
                              void* d_out, int out_size, void* d_ws, size_t ws_size,
                              hipStream_t stream) {
    const float* x_old     = (const float*)d_in[0];
    const float* y_old     = (const float*)d_in[1];
    const float* x_old_dot = (const float*)d_in[2];
    const float* omega     = (const float*)d_in[3];
    const float* A         = (const float*)d_in[4];
    const float* b         = (const float*)d_in[5];
    const float* pd        = (const float*)d_in[7];
    const float* h_a       = (const float*)d_in[6];
    const float* y_state   = (const float*)d_in[9];
    float* out = (float*)d_out;
    float2* rphi = (float2*)d_ws;
    float2* uv   = (float2*)((char*)d_ws + NN * sizeof(float2));

    prep_uv<<<NN / 256, 256, 0, stream>>>(x_old, y_old, b, rphi, uv);
    cpg_rows<<<NN / RPB, 256, 0, stream>>>(pd, rphi, uv, x_old, y_old, x_old_dot,
                                           omega, A, b, h_a, y_state, out);
}

// Round 4
// 17.770 us; speedup vs baseline: 1.2411x; 1.2254x over previous
//
#include <hip/hip_runtime.h>
#include <math.h>

#define NN 4096
#define ALPHA_C 1.0f
#define H_COUP_C 0.1f
#define DT_C 0.01f
#define RPB 4   // rows per block

// Single fused kernel. Row i of the live (odd) part of (K+R)@sv:
//   dot_odd[i] = kd_i*v_i + wz_i*u_i
//              + H*[ sum_j ( sin(pd[i,j])*u_j + cos(pd[i,j])*v_j )
//                    - (sin(pd_ii)*u_i + cos(pd_ii)*v_i) + v_i ]
// where u_j = sv[2j], v_j = sv[2j+1]:
//   j < N/2 : (u,v) = ((float2*)x_old)[j]
//   j >= N/2: (u,v) = ((float2*)y_old)[j-N/2] - ((float2*)b)[j-N/2]
__global__ __launch_bounds__(256) void cpg_fused(
        const float* __restrict__ pd,
        const float* __restrict__ x_old,
        const float* __restrict__ y_old,
        const float* __restrict__ x_old_dot,
        const float* __restrict__ omega,
        const float* __restrict__ A,
        const float* __restrict__ b,
        const float* __restrict__ h_a,
        const float* __restrict__ y_state,
        float* __restrict__ out) {
    const int tid = threadIdx.x;

    // uv table in LDS, transposed layout: slot s(j) = (j>>2) + (j&3)*1024,
    // float2 (u,v) at lds_uv[2*s]. Per-element reads in the main loop are then
    // 8B-stride within a wave -> 2-way bank alias (free).
    __shared__ float lds_uv[2 * NN];        // 32 KB
    __shared__ float wsum[4][RPB];

    // Phase A: stage uv straight from sources (j0 = 2m, j1 = 2m+1)
    const float4* x4 = reinterpret_cast<const float4*>(x_old);
    const float4* y4 = reinterpret_cast<const float4*>(y_old);
    const float4* b4 = reinterpret_cast<const float4*>(b);
    #pragma unroll
    for (int k = 0; k < 8; ++k) {
        int m = k * 256 + tid;              // 0..2047
        float4 t4;
        if (m < 1024) {
            t4 = x4[m];
        } else {
            float4 ya = y4[m - 1024];
            float4 bb = b4[m - 1024];
            t4 = make_float4(ya.x - bb.x, ya.y - bb.y, ya.z - bb.z, ya.w - bb.w);
        }
        int s0 = (m >> 1) + (m & 1) * 2048; // slot of j0 = 2m
        int s1 = s0 + 1024;                 // slot of j1 = 2m+1
        *reinterpret_cast<float2*>(&lds_uv[2 * s0]) = make_float2(t4.x, t4.y);
        *reinterpret_cast<float2*>(&lds_uv[2 * s1]) = make_float2(t4.z, t4.w);
    }
    __syncthreads();

    // Phase B: 4 rows per block, k-outer so each LDS read feeds 4 rows
    const int row0 = blockIdx.x * RPB;
    const float* __restrict__ prow = pd + (size_t)row0 * NN;
    float acc[RPB] = {0.f, 0.f, 0.f, 0.f};
    #pragma unroll
    for (int k = 0; k < 4; ++k) {
        const int sbase = k * 256 + tid;    // = jb>>2
        const int jb = sbase * 4;
        float2 uv0 = *reinterpret_cast<const float2*>(&lds_uv[2 * sbase]);
        float2 uv1 = *reinterpret_cast<const float2*>(&lds_uv[2 * (sbase + 1024)]);
        float2 uv2 = *reinterpret_cast<const float2*>(&lds_uv[2 * (sbase + 2048)]);
        float2 uv3 = *reinterpret_cast<const float2*>(&lds_uv[2 * (sbase + 3072)]);
        #pragma unroll
        for (int r = 0; r < RPB; ++r) {
            float4 p4 = *reinterpret_cast<const float4*>(prow + (size_t)r * NN + jb);
            float a = acc[r];
            a = fmaf(__sinf(p4.x), uv0.x, a);
            a = fmaf(__cosf(p4.x), uv0.y, a);
            a = fmaf(__sinf(p4.y), uv1.x, a);
            a = fmaf(__cosf(p4.y), uv1.y, a);
            a = fmaf(__sinf(p4.z), uv2.x, a);
            a = fmaf(__cosf(p4.z), uv2.y, a);
            a = fmaf(__sinf(p4.w), uv3.x, a);
            a = fmaf(__cosf(p4.w), uv3.y, a);
            acc[r] = a;
        }
    }

    // wave butterfly reduce, per row
    #pragma unroll
    for (int r = 0; r < RPB; ++r) {
        #pragma unroll
        for (int off = 32; off > 0; off >>= 1)
            acc[r] += __shfl_xor(acc[r], off, 64);
    }
    const int wid = tid >> 6;
    if ((tid & 63) == 0) {
        #pragma unroll
        for (int r = 0; r < RPB; ++r) wsum[wid][r] = acc[r];
    }
    __syncthreads();

    if (tid < RPB) {
        const int r = tid;
        const int i = row0 + r;
        float total = wsum[0][r] + wsum[1][r] + wsum[2][r] + wsum[3][r];
        // (u,v) for column i from LDS
        int si = (i >> 2) + (i & 3) * 1024;
        float2 uvi = *reinterpret_cast<const float2*>(&lds_uv[2 * si]);
        // diagonal: reference forces pd_ii = 0 -> contribution v_i
        float pii = pd[(size_t)i * NN + i];
        total -= __sinf(pii) * uvi.x + __cosf(pii) * uvi.y;
        total += uvi.y;

        float xo = x_old[i], yo = y_old[i], bi = b[i];
        float ym = yo - bi;
        float r_sq = xo * xo + ym * ym;
        float kd = ALPHA_C * (1.0f - r_sq);
        float zeta = 1.0f - h_a[i] * (xo / (fabsf(x_old_dot[i]) + 1e-9f));
        float wz = omega[i] / zeta;
        float dot = kd * uvi.y + wz * uvi.x + H_COUP_C * total;
        float m = 2.0f * omega[i];
        dot = fminf(fmaxf(dot, -m), m);
        float y_new = y_state[i] + (dot + bi) * DT_C;
        out[i] = A[i] * y_new;
    }
}

extern "C" void kernel_launch(void* const* d_in, const int* in_sizes, int n_in,
                              void* d_out, int out_size, void* d_ws, size_t ws_size,
                              hipStream_t stream) {
    const float* x_old     = (const float*)d_in[0];
    const float* y_old     = (const float*)d_in[1];
    const float* x_old_dot = (const float*)d_in[2];
    const float* omega     = (const float*)d_in[3];
    const float* A         = (const float*)d_in[4];
    const float* b         = (const float*)d_in[5];
    const float* h_a       = (const float*)d_in[6];
    const float* pd        = (const float*)d_in[7];
    const float* y_state   = (const float*)d_in[9];
    float* out = (float*)d_out;

    cpg_fused<<<NN / RPB, 256, 0, stream>>>(pd, x_old, y_old, x_old_dot,
                                            omega, A, b, h_a, y_state, out);
}